// Round 1
// baseline (339.786 us; speedup 1.0000x reference)
//
#include <hip/hip_runtime.h>
#include <hip/hip_bf16.h>

typedef __bf16 bf16x8 __attribute__((ext_vector_type(8)));
typedef float  f32x4  __attribute__((ext_vector_type(4)));

#define LOG2E 1.4426950408889634f
#define N4096 4096

__device__ __forceinline__ void gl_lds16(const void* g, void* l) {
  __builtin_amdgcn_global_load_lds(
      (const __attribute__((address_space(1))) void*)g,
      (__attribute__((address_space(3))) void*)l, 16, 0, 0);
}

// ---------------- K1: z = xf @ proj_w + proj_b ; sq = rowsum(z*z) -------------
__global__ __launch_bounds__(256) void zproj_kernel(
    const float* __restrict__ x, const float* __restrict__ pw,
    const float* __restrict__ pb, float* __restrict__ z, float* __restrict__ sq)
{
  int wv = threadIdx.x >> 6, lane = threadIdx.x & 63;
  int row = blockIdx.x * 4 + wv;
  const float* xr = x + (size_t)row * N4096;
  float acc[16];
#pragma unroll
  for (int l = 0; l < 16; ++l) acc[l] = 0.f;
  for (int k = lane; k < N4096; k += 64) {
    float xv = xr[k];
    const float4* wp = (const float4*)(pw + (size_t)k * 16);
    float4 a = wp[0], b = wp[1], c = wp[2], d = wp[3];
    acc[0]  += xv * a.x; acc[1]  += xv * a.y; acc[2]  += xv * a.z; acc[3]  += xv * a.w;
    acc[4]  += xv * b.x; acc[5]  += xv * b.y; acc[6]  += xv * b.z; acc[7]  += xv * b.w;
    acc[8]  += xv * c.x; acc[9]  += xv * c.y; acc[10] += xv * c.z; acc[11] += xv * c.w;
    acc[12] += xv * d.x; acc[13] += xv * d.y; acc[14] += xv * d.z; acc[15] += xv * d.w;
  }
#pragma unroll
  for (int l = 0; l < 16; ++l) {
    float v = acc[l];
#pragma unroll
    for (int off = 32; off; off >>= 1) v += __shfl_xor(v, off, 64);
    acc[l] = v;
  }
  if (lane == 0) {
    float s = 0.f;
#pragma unroll
    for (int l = 0; l < 16; ++l) {
      float zv = acc[l] + pb[l];
      z[(size_t)row * 16 + l] = zv;
      s += zv * zv;
    }
    sq[row] = s;
  }
}

// ------- K2: q_i = sum_j exp(-d2_ij); pi_i = sigmoid MLP; dvec = pi/q ---------
__global__ __launch_bounds__(256) void piq_kernel(
    const float* __restrict__ z, const float* __restrict__ sq,
    const float* __restrict__ w1, const float* __restrict__ b1,
    const float* __restrict__ w2, const float* __restrict__ b2p,
    float* __restrict__ dvec)
{
  __shared__ float zi[8][16];
  __shared__ float sqi[8];
  __shared__ float red[2][8][4];
  int tid = threadIdx.x;
  int i0 = blockIdx.x * 8;
  if (tid < 128) zi[tid >> 4][tid & 15] = z[(size_t)i0 * 16 + tid];
  if (tid < 8) sqi[tid] = sq[i0 + tid];
  __syncthreads();
  float accq[8], accp[8];
#pragma unroll
  for (int r = 0; r < 8; ++r) { accq[r] = 0.f; accp[r] = 0.f; }
  for (int jt = 0; jt < 16; ++jt) {
    int j = jt * 256 + tid;
    const float4* zp = (const float4*)(z + (size_t)j * 16);
    float4 z0 = zp[0], z1 = zp[1], z2 = zp[2], z3 = zp[3];
    float zj[16];
    zj[0]=z0.x; zj[1]=z0.y; zj[2]=z0.z; zj[3]=z0.w;
    zj[4]=z1.x; zj[5]=z1.y; zj[6]=z1.z; zj[7]=z1.w;
    zj[8]=z2.x; zj[9]=z2.y; zj[10]=z2.z; zj[11]=z2.w;
    zj[12]=z3.x; zj[13]=z3.y; zj[14]=z3.z; zj[15]=z3.w;
    float sqj = sq[j];
    float b1j = b1[j], w2j = w2[j];
    float wc[16];
#pragma unroll
    for (int l = 0; l < 16; ++l) wc[l] = w1[(size_t)l * N4096 + j];
#pragma unroll
    for (int r = 0; r < 8; ++r) {
      float dz = 0.f, dw = 0.f;
#pragma unroll
      for (int l = 0; l < 16; ++l) { dz += zi[r][l] * zj[l]; dw += zi[r][l] * wc[l]; }
      accq[r] += exp2f(-LOG2E * (sqi[r] + sqj - 2.f * dz));
      float t = dw + b1j;
      accp[r] += fmaxf(t, 0.f) * w2j;
    }
  }
  int lane = tid & 63, wv = tid >> 6;
#pragma unroll
  for (int r = 0; r < 8; ++r) {
    float a = accq[r], b = accp[r];
#pragma unroll
    for (int off = 32; off; off >>= 1) { a += __shfl_xor(a, off, 64); b += __shfl_xor(b, off, 64); }
    if (lane == 0) { red[0][r][wv] = a; red[1][r][wv] = b; }
  }
  __syncthreads();
  if (tid < 8) {
    float q = red[0][tid][0] + red[0][tid][1] + red[0][tid][2] + red[0][tid][3];
    float p = red[1][tid][0] + red[1][tid][1] + red[1][tid][2] + red[1][tid][3];
    float logit = p + b2p[0];
    float pi = 1.f / (1.f + exp2f(-LOG2E * logit));
    dvec[i0 + tid] = pi / q;
  }
}

// ---------------- K3: XFT[n][k] = bf16(xf[k][n]) ------------------------------
__global__ __launch_bounds__(256) void transpose_kernel(
    const float* __restrict__ x, __hip_bfloat16* __restrict__ xft)
{
  __shared__ float t[64][65];
  int bk = blockIdx.x & 63, bn = blockIdx.x >> 6;
  int tid = threadIdx.x;
  int c = tid & 63, r4 = tid >> 6;
  const float* src = x + (size_t)(bk * 64 + r4) * N4096 + bn * 64 + c;
#pragma unroll
  for (int p = 0; p < 16; ++p)
    t[r4 + p * 4][c] = src[(size_t)p * 4 * N4096];
  __syncthreads();
  __hip_bfloat16* dst = xft + (size_t)(bn * 64 + r4) * N4096 + bk * 64 + c;
#pragma unroll
  for (int p = 0; p < 16; ++p)
    dst[(size_t)p * 4 * N4096] = __float2bfloat16(t[c][r4 + p * 4]);
}

// ------- K4: W[i][j] = bf16(exp(-d2_ij)*dvec[j]); rowscale = 4*dt/(D+1e-5) ----
__global__ __launch_bounds__(256) void wmat_kernel(
    const float* __restrict__ z, const float* __restrict__ sq,
    const float* __restrict__ dvec, const float* __restrict__ dtp,
    __hip_bfloat16* __restrict__ W, float* __restrict__ rowscale)
{
  __shared__ float zi[8][16];
  __shared__ float sqi[8];
  __shared__ float red[8][4];
  int tid = threadIdx.x;
  int i0 = blockIdx.x * 8;
  if (tid < 128) zi[tid >> 4][tid & 15] = z[(size_t)i0 * 16 + tid];
  if (tid < 8) sqi[tid] = sq[i0 + tid];
  __syncthreads();
  float accD[8];
#pragma unroll
  for (int r = 0; r < 8; ++r) accD[r] = 0.f;
  for (int jt = 0; jt < 16; ++jt) {
    int j = jt * 256 + tid;
    const float4* zp = (const float4*)(z + (size_t)j * 16);
    float4 z0 = zp[0], z1 = zp[1], z2 = zp[2], z3 = zp[3];
    float zj[16];
    zj[0]=z0.x; zj[1]=z0.y; zj[2]=z0.z; zj[3]=z0.w;
    zj[4]=z1.x; zj[5]=z1.y; zj[6]=z1.z; zj[7]=z1.w;
    zj[8]=z2.x; zj[9]=z2.y; zj[10]=z2.z; zj[11]=z2.w;
    zj[12]=z3.x; zj[13]=z3.y; zj[14]=z3.z; zj[15]=z3.w;
    float sqj = sq[j], dvj = dvec[j];
#pragma unroll
    for (int r = 0; r < 8; ++r) {
      float dz = 0.f;
#pragma unroll
      for (int l = 0; l < 16; ++l) dz += zi[r][l] * zj[l];
      float w = exp2f(-LOG2E * (sqi[r] + sqj - 2.f * dz)) * dvj;
      W[(size_t)(i0 + r) * N4096 + j] = __float2bfloat16(w);
      accD[r] += w;
    }
  }
  int lane = tid & 63, wv = tid >> 6;
#pragma unroll
  for (int r = 0; r < 8; ++r) {
    float a = accD[r];
#pragma unroll
    for (int off = 32; off; off >>= 1) a += __shfl_xor(a, off, 64);
    if (lane == 0) red[r][wv] = a;
  }
  __syncthreads();
  if (tid < 8) {
    float D = red[tid][0] + red[tid][1] + red[tid][2] + red[tid][3] + 1e-5f;
    rowscale[i0 + tid] = 4.f * dtp[0] / D;
  }
}

// ---------------- K5: out = x*(1-dt) + rowscale[i] * (W @ XFT^T) --------------
// A = W [4096][4096] bf16 row-major (K-contig), B^T = XFT [4096][4096] bf16
// 128x128 tile, BK=64, 4 waves 2x2, XOR-swizzled LDS (both sides).
__global__ __launch_bounds__(256) void gemm_kernel(
    const __hip_bfloat16* __restrict__ Wm, const __hip_bfloat16* __restrict__ BT,
    const float* __restrict__ x, const float* __restrict__ rowscale,
    const float* __restrict__ dtp, float* __restrict__ out)
{
  __shared__ __bf16 sA[128 * 64];
  __shared__ __bf16 sB[128 * 64];
  int b = blockIdx.x;
  int swz = (b & 7) * 128 + (b >> 3);      // XCD-aware (1024 % 8 == 0, bijective)
  int tm = swz >> 5, tn = swz & 31;
  int tid = threadIdx.x;
  int lane = tid & 63, wv = tid >> 6;
  int wr = wv >> 1, wc = wv & 1;
  int g = lane >> 4, rr = lane & 15;

  f32x4 acc[4][4];
#pragma unroll
  for (int i = 0; i < 4; ++i)
#pragma unroll
    for (int j = 0; j < 4; ++j) acc[i][j] = (f32x4){0.f, 0.f, 0.f, 0.f};

  const __hip_bfloat16* Ab = Wm + (size_t)tm * 128 * N4096;
  const __hip_bfloat16* Bb = BT + (size_t)tn * 128 * N4096;

  int crow[4], ccol[4];
#pragma unroll
  for (int s = 0; s < 4; ++s) {
    int c = s * 256 + tid;
    crow[s] = c >> 3;
    ccol[s] = ((c & 7) ^ (crow[s] & 7)) * 8;   // pre-swizzled global source
  }

  for (int kt = 0; kt < 64; ++kt) {
    int k0 = kt * 64;
    __syncthreads();
#pragma unroll
    for (int s = 0; s < 4; ++s) {
      int c = s * 256 + tid;
      gl_lds16(Ab + (size_t)crow[s] * N4096 + k0 + ccol[s], &sA[c * 8]);
      gl_lds16(Bb + (size_t)crow[s] * N4096 + k0 + ccol[s], &sB[c * 8]);
    }
    __syncthreads();
#pragma unroll
    for (int kh = 0; kh < 2; ++kh) {
      bf16x8 af[4], bfr[4];
      int slot = (kh * 4 + g) ^ (rr & 7);      // swizzled read slot
#pragma unroll
      for (int mi = 0; mi < 4; ++mi) {
        int row = wr * 64 + mi * 16 + rr;
        af[mi] = *(const bf16x8*)&sA[row * 64 + slot * 8];
      }
#pragma unroll
      for (int ni = 0; ni < 4; ++ni) {
        int row = wc * 64 + ni * 16 + rr;
        bfr[ni] = *(const bf16x8*)&sB[row * 64 + slot * 8];
      }
#pragma unroll
      for (int mi = 0; mi < 4; ++mi)
#pragma unroll
        for (int ni = 0; ni < 4; ++ni)
          acc[mi][ni] = __builtin_amdgcn_mfma_f32_16x16x32_bf16(
              af[mi], bfr[ni], acc[mi][ni], 0, 0, 0);
    }
  }
  float dtv = dtp[0];
  float omd = 1.0f - dtv;
#pragma unroll
  for (int mi = 0; mi < 4; ++mi) {
#pragma unroll
    for (int r4 = 0; r4 < 4; ++r4) {
      int row = tm * 128 + wr * 64 + mi * 16 + g * 4 + r4;
      float rs = rowscale[row];
      const float* xr = x + (size_t)row * N4096;
      float* orow = out + (size_t)row * N4096;
#pragma unroll
      for (int ni = 0; ni < 4; ++ni) {
        int col = tn * 128 + wc * 64 + ni * 16 + rr;
        orow[col] = xr[col] * omd + rs * acc[mi][ni][r4];
      }
    }
  }
}

extern "C" void kernel_launch(void* const* d_in, const int* in_sizes, int n_in,
                              void* d_out, int out_size, void* d_ws, size_t ws_size,
                              hipStream_t stream) {
  const float* x      = (const float*)d_in[0];
  const float* proj_w = (const float*)d_in[1];
  const float* proj_b = (const float*)d_in[2];
  const float* pi_w1  = (const float*)d_in[3];
  const float* pi_b1  = (const float*)d_in[4];
  const float* pi_w2  = (const float*)d_in[5];
  const float* pi_b2  = (const float*)d_in[6];
  const float* dt     = (const float*)d_in[7];
  float* out = (float*)d_out;

  char* ws = (char*)d_ws;
  const size_t MB = 1024 * 1024;
  __hip_bfloat16* W   = (__hip_bfloat16*)(ws);               // 32 MB
  __hip_bfloat16* XFT = (__hip_bfloat16*)(ws + 32 * MB);     // 32 MB
  float* z        = (float*)(ws + 64 * MB);                  // 256 KB
  float* sq       = (float*)(ws + 64 * MB + 256 * 1024);     // 16 KB
  float* dvec     = (float*)(ws + 64 * MB + 272 * 1024);     // 16 KB
  float* rowscale = (float*)(ws + 64 * MB + 288 * 1024);     // 16 KB

  zproj_kernel<<<1024, 256, 0, stream>>>(x, proj_w, proj_b, z, sq);
  piq_kernel<<<512, 256, 0, stream>>>(z, sq, pi_w1, pi_b1, pi_w2, pi_b2, dvec);
  transpose_kernel<<<4096, 256, 0, stream>>>(x, XFT);
  wmat_kernel<<<512, 256, 0, stream>>>(z, sq, dvec, dt, W, rowscale);
  gemm_kernel<<<1024, 256, 0, stream>>>(W, XFT, x, rowscale, dt, out);
}

// Round 2
// 297.360 us; speedup vs baseline: 1.1427x; 1.1427x over previous
//
#include <hip/hip_runtime.h>
#include <hip/hip_bf16.h>

typedef __bf16 bf16x8 __attribute__((ext_vector_type(8)));
typedef float  f32x4  __attribute__((ext_vector_type(4)));

#define LOG2E 1.4426950408889634f
#define N4096 4096
#define NT 64

__device__ __forceinline__ void gl_lds16(const void* g, void* l) {
  __builtin_amdgcn_global_load_lds(
      (const __attribute__((address_space(1))) void*)g,
      (__attribute__((address_space(3))) void*)l, 16, 0, 0);
}

__device__ __forceinline__ void bar() {
  asm volatile("" ::: "memory");
  __builtin_amdgcn_s_barrier();
  asm volatile("" ::: "memory");
}

// ---------------- K1: z = xf @ proj_w + proj_b ; sq = rowsum(z*z) -------------
// 4 rows per wave in ONE k-sweep: proj_w swept once per 4 rows (256 MB L2 total).
__global__ __launch_bounds__(256) void zproj_kernel(
    const float* __restrict__ x, const float* __restrict__ pw,
    const float* __restrict__ pb, float* __restrict__ z, float* __restrict__ sq)
{
  int wv = threadIdx.x >> 6, lane = threadIdx.x & 63;
  int row0 = blockIdx.x * 16 + wv * 4;
  const float* xr0 = x + (size_t)row0 * N4096;
  const float* xr1 = xr0 + N4096;
  const float* xr2 = xr1 + N4096;
  const float* xr3 = xr2 + N4096;
  float acc[4][16];
#pragma unroll
  for (int r = 0; r < 4; ++r)
#pragma unroll
    for (int l = 0; l < 16; ++l) acc[r][l] = 0.f;
  for (int k = lane; k < N4096; k += 64) {
    const float4* wp = (const float4*)(pw + (size_t)k * 16);
    float4 a = wp[0], b = wp[1], c = wp[2], d = wp[3];
    float w[16] = {a.x,a.y,a.z,a.w,b.x,b.y,b.z,b.w,c.x,c.y,c.z,c.w,d.x,d.y,d.z,d.w};
    float xv[4] = {xr0[k], xr1[k], xr2[k], xr3[k]};
#pragma unroll
    for (int r = 0; r < 4; ++r)
#pragma unroll
      for (int l = 0; l < 16; ++l) acc[r][l] += xv[r] * w[l];
  }
#pragma unroll
  for (int r = 0; r < 4; ++r)
#pragma unroll
    for (int l = 0; l < 16; ++l) {
      float v = acc[r][l];
#pragma unroll
      for (int off = 32; off; off >>= 1) v += __shfl_xor(v, off, 64);
      acc[r][l] = v;
    }
  if (lane == 0) {
#pragma unroll
    for (int r = 0; r < 4; ++r) {
      float s = 0.f;
#pragma unroll
      for (int l = 0; l < 16; ++l) {
        float zv = acc[r][l] + pb[l];
        z[(size_t)(row0 + r) * 16 + l] = zv;
        s += zv * zv;
      }
      sq[row0 + r] = s;
    }
  }
}

// ------- K2: q_i = sum_j exp(-d2_ij); pi_i = sigmoid MLP; dvec = pi/q ---------
// 8 i-rows per block held in REGISTERS (no LDS-read storm).
__global__ __launch_bounds__(256, 2) void piq_kernel(
    const float* __restrict__ z, const float* __restrict__ sq,
    const float* __restrict__ w1, const float* __restrict__ b1,
    const float* __restrict__ w2, const float* __restrict__ b2p,
    float* __restrict__ dvec)
{
  __shared__ float red[2][8][4];
  int tid = threadIdx.x;
  int i0 = blockIdx.x * 8;
  float zi[8][16], sqi[8];
#pragma unroll
  for (int r = 0; r < 8; ++r) {
    const float4* zp = (const float4*)(z + (size_t)(i0 + r) * 16);
    float4 a = zp[0], b = zp[1], c = zp[2], d = zp[3];
    zi[r][0]=a.x; zi[r][1]=a.y; zi[r][2]=a.z; zi[r][3]=a.w;
    zi[r][4]=b.x; zi[r][5]=b.y; zi[r][6]=b.z; zi[r][7]=b.w;
    zi[r][8]=c.x; zi[r][9]=c.y; zi[r][10]=c.z; zi[r][11]=c.w;
    zi[r][12]=d.x; zi[r][13]=d.y; zi[r][14]=d.z; zi[r][15]=d.w;
    sqi[r] = sq[i0 + r];
  }
  float accq[8], accp[8];
#pragma unroll
  for (int r = 0; r < 8; ++r) { accq[r] = 0.f; accp[r] = 0.f; }
  for (int jt = 0; jt < 16; ++jt) {
    int j = jt * 256 + tid;
    const float4* zp = (const float4*)(z + (size_t)j * 16);
    float4 z0 = zp[0], z1 = zp[1], z2 = zp[2], z3 = zp[3];
    float zj[16];
    zj[0]=z0.x; zj[1]=z0.y; zj[2]=z0.z; zj[3]=z0.w;
    zj[4]=z1.x; zj[5]=z1.y; zj[6]=z1.z; zj[7]=z1.w;
    zj[8]=z2.x; zj[9]=z2.y; zj[10]=z2.z; zj[11]=z2.w;
    zj[12]=z3.x; zj[13]=z3.y; zj[14]=z3.z; zj[15]=z3.w;
    float sqj = sq[j], b1j = b1[j], w2j = w2[j];
    float dz[8], dw[8];
#pragma unroll
    for (int r = 0; r < 8; ++r) { dz[r] = 0.f; dw[r] = 0.f; }
#pragma unroll
    for (int l = 0; l < 16; ++l) {
      float wl = w1[(size_t)l * N4096 + j];
      float zjl = zj[l];
#pragma unroll
      for (int r = 0; r < 8; ++r) { dz[r] += zi[r][l] * zjl; dw[r] += zi[r][l] * wl; }
    }
#pragma unroll
    for (int r = 0; r < 8; ++r) {
      accq[r] += exp2f(-LOG2E * (sqi[r] + sqj - 2.f * dz[r]));
      accp[r] += fmaxf(dw[r] + b1j, 0.f) * w2j;
    }
  }
  int lane = tid & 63, wv = tid >> 6;
#pragma unroll
  for (int r = 0; r < 8; ++r) {
    float a = accq[r], b = accp[r];
#pragma unroll
    for (int off = 32; off; off >>= 1) { a += __shfl_xor(a, off, 64); b += __shfl_xor(b, off, 64); }
    if (lane == 0) { red[0][r][wv] = a; red[1][r][wv] = b; }
  }
  __syncthreads();
  if (tid < 8) {
    float q = red[0][tid][0] + red[0][tid][1] + red[0][tid][2] + red[0][tid][3];
    float p = red[1][tid][0] + red[1][tid][1] + red[1][tid][2] + red[1][tid][3];
    float logit = p + b2p[0];
    float pi = 1.f / (1.f + exp2f(-LOG2E * logit));
    dvec[i0 + tid] = pi / q;
  }
}

// ---------------- K3: XFT[n][k] = bf16(xf[k][n]) ------------------------------
__global__ __launch_bounds__(256) void transpose_kernel(
    const float* __restrict__ x, __hip_bfloat16* __restrict__ xft)
{
  __shared__ float t[64][65];
  int bk = blockIdx.x & 63, bn = blockIdx.x >> 6;
  int tid = threadIdx.x;
  int c = tid & 63, r4 = tid >> 6;
  const float* src = x + (size_t)(bk * 64 + r4) * N4096 + bn * 64 + c;
#pragma unroll
  for (int p = 0; p < 16; ++p)
    t[r4 + p * 4][c] = src[(size_t)p * 4 * N4096];
  __syncthreads();
  __hip_bfloat16* dst = xft + (size_t)(bn * 64 + r4) * N4096 + bk * 64 + c;
#pragma unroll
  for (int p = 0; p < 16; ++p)
    dst[(size_t)p * 4 * N4096] = __float2bfloat16(t[c][r4 + p * 4]);
}

// ------- K4: W[i][j] = bf16(exp(-d2_ij)*dvec[j]); rowscale = 4*dt/(D+1e-5) ----
__global__ __launch_bounds__(256, 2) void wmat_kernel(
    const float* __restrict__ z, const float* __restrict__ sq,
    const float* __restrict__ dvec, const float* __restrict__ dtp,
    __hip_bfloat16* __restrict__ W, float* __restrict__ rowscale)
{
  __shared__ float red[8][4];
  int tid = threadIdx.x;
  int i0 = blockIdx.x * 8;
  float zi[8][16], sqi[8];
#pragma unroll
  for (int r = 0; r < 8; ++r) {
    const float4* zp = (const float4*)(z + (size_t)(i0 + r) * 16);
    float4 a = zp[0], b = zp[1], c = zp[2], d = zp[3];
    zi[r][0]=a.x; zi[r][1]=a.y; zi[r][2]=a.z; zi[r][3]=a.w;
    zi[r][4]=b.x; zi[r][5]=b.y; zi[r][6]=b.z; zi[r][7]=b.w;
    zi[r][8]=c.x; zi[r][9]=c.y; zi[r][10]=c.z; zi[r][11]=c.w;
    zi[r][12]=d.x; zi[r][13]=d.y; zi[r][14]=d.z; zi[r][15]=d.w;
    sqi[r] = sq[i0 + r];
  }
  float accD[8];
#pragma unroll
  for (int r = 0; r < 8; ++r) accD[r] = 0.f;
  for (int jt = 0; jt < 16; ++jt) {
    int j = jt * 256 + tid;
    const float4* zp = (const float4*)(z + (size_t)j * 16);
    float4 z0 = zp[0], z1 = zp[1], z2 = zp[2], z3 = zp[3];
    float zj[16];
    zj[0]=z0.x; zj[1]=z0.y; zj[2]=z0.z; zj[3]=z0.w;
    zj[4]=z1.x; zj[5]=z1.y; zj[6]=z1.z; zj[7]=z1.w;
    zj[8]=z2.x; zj[9]=z2.y; zj[10]=z2.z; zj[11]=z2.w;
    zj[12]=z3.x; zj[13]=z3.y; zj[14]=z3.z; zj[15]=z3.w;
    float sqj = sq[j], dvj = dvec[j];
    float dz[8];
#pragma unroll
    for (int r = 0; r < 8; ++r) dz[r] = 0.f;
#pragma unroll
    for (int l = 0; l < 16; ++l) {
      float zjl = zj[l];
#pragma unroll
      for (int r = 0; r < 8; ++r) dz[r] += zi[r][l] * zjl;
    }
#pragma unroll
    for (int r = 0; r < 8; ++r) {
      float w = exp2f(-LOG2E * (sqi[r] + sqj - 2.f * dz[r])) * dvj;
      W[(size_t)(i0 + r) * N4096 + j] = __float2bfloat16(w);
      accD[r] += w;
    }
  }
  int lane = tid & 63, wv = tid >> 6;
#pragma unroll
  for (int r = 0; r < 8; ++r) {
    float a = accD[r];
#pragma unroll
    for (int off = 32; off; off >>= 1) a += __shfl_xor(a, off, 64);
    if (lane == 0) red[r][wv] = a;
  }
  __syncthreads();
  if (tid < 8) {
    float D = red[tid][0] + red[tid][1] + red[tid][2] + red[tid][3] + 1e-5f;
    rowscale[i0 + tid] = 4.f * dtp[0] / D;
  }
}

// ---------------- K5: out = x*(1-dt) + rowscale[i] * (W @ XFT^T) --------------
// 256x256 tile, BK=64, 8 waves (2Mx4N), 8-phase schedule, counted vmcnt(6),
// raw s_barrier, setprio around MFMA clusters, XOR-swizzled LDS (both sides).
__global__ __launch_bounds__(512, 2) void gemm8_kernel(
    const __hip_bfloat16* __restrict__ Wm, const __hip_bfloat16* __restrict__ BT,
    const float* __restrict__ x, const float* __restrict__ rowscale,
    const float* __restrict__ dtp, float* __restrict__ out)
{
  extern __shared__ __bf16 S[];   // [2 bufs][A 16384 | B 16384] = 128 KB
  const int b0 = blockIdx.x;
  const int swz = (b0 & 7) * 32 + (b0 >> 3);   // 256 % 8 == 0: bijective
  const int tm = swz & 15, tn = swz >> 4;
  const int tid = threadIdx.x;
  const int lane = tid & 63;
  const int wv = tid >> 6;
  const int wr = wv >> 2, wc = wv & 3;         // 2 x 4 waves
  const int g = lane >> 4, rr = lane & 15;

  const int srow = tid >> 3;                   // 0..63 within a 64-row unit
  const int lslot = tid & 7;                   // linear LDS slot (8 bf16 each)

  const __hip_bfloat16* Abase = Wm + (size_t)(tm * 256) * N4096;
  const __hip_bfloat16* Bbase = BT + (size_t)(tn * 256) * N4096;

  auto stageA = [&](int tk, int R0) {
    int r = R0 + srow;
    int gc = lslot ^ (r & 7);                  // pre-swizzled global source
    gl_lds16(Abase + (size_t)r * N4096 + tk * 64 + gc * 8,
             S + (size_t)(tk & 1) * 32768 + r * 64 + lslot * 8);
  };
  auto stageB = [&](int tk, int R0) {
    int r = R0 + srow;
    int gc = lslot ^ (r & 7);
    gl_lds16(Bbase + (size_t)r * N4096 + tk * 64 + gc * 8,
             S + (size_t)(tk & 1) * 32768 + 16384 + r * 64 + lslot * 8);
  };

  f32x4 acc[8][4];
#pragma unroll
  for (int i = 0; i < 8; ++i)
#pragma unroll
    for (int j = 0; j < 4; ++j) acc[i][j] = (f32x4){0.f, 0.f, 0.f, 0.f};

  // Prologue: tile0 full (8 units), tile1 partial (6 units, steady-state order)
  stageA(0, 0); stageA(0, 64); stageA(0, 128); stageA(0, 192);
  stageB(0, 0); stageB(0, 64); stageB(0, 128); stageB(0, 192);
  stageB(1, 0); stageB(1, 64); stageB(1, 128); stageB(1, 192);
  stageA(1, 0); stageA(1, 128);
  asm volatile("s_waitcnt vmcnt(6)" ::: "memory");
  bar();

  for (int t = 0; t < NT; ++t) {
    const __bf16* sAb = S + (size_t)(t & 1) * 32768;
    const __bf16* sBb = sAb + 16384;
    bf16x8 bfrag[4][2];

#define APHASE(q)                                                              \
    {                                                                          \
      bf16x8 af[2][2];                                                         \
      _Pragma("unroll")                                                        \
      for (int mi2 = 0; mi2 < 2; ++mi2) {                                      \
        _Pragma("unroll")                                                      \
        for (int kh = 0; kh < 2; ++kh) {                                       \
          int row_ = wr * 128 + ((q) * 2 + mi2) * 16 + rr;                     \
          int slot_ = ((kh << 2) | g) ^ (rr & 7);                              \
          af[mi2][kh] = *(const bf16x8*)(sAb + row_ * 64 + slot_ * 8);         \
        }                                                                      \
      }                                                                        \
      bar();                                                                   \
      __builtin_amdgcn_s_setprio(1);                                          \
      _Pragma("unroll")                                                        \
      for (int kh = 0; kh < 2; ++kh)                                           \
        _Pragma("unroll")                                                      \
        for (int mi2 = 0; mi2 < 2; ++mi2)                                      \
          _Pragma("unroll")                                                    \
          for (int ni = 0; ni < 4; ++ni)                                       \
            acc[(q) * 2 + mi2][ni] = __builtin_amdgcn_mfma_f32_16x16x32_bf16(  \
                af[mi2][kh], bfrag[ni][kh], acc[(q) * 2 + mi2][ni], 0, 0, 0);  \
      __builtin_amdgcn_s_setprio(0);                                          \
    }

    // ---- phase 0: stage tile t+1's last two A units; read B + A-quadrant 0
    if (t + 1 < NT) { stageA(t + 1, 64); stageA(t + 1, 192); }
#pragma unroll
    for (int ni = 0; ni < 4; ++ni)
#pragma unroll
      for (int kh = 0; kh < 2; ++kh) {
        int row_ = wc * 64 + ni * 16 + rr;
        int slot_ = ((kh << 2) | g) ^ (rr & 7);
        bfrag[ni][kh] = *(const bf16x8*)(sBb + row_ * 64 + slot_ * 8);
      }
    APHASE(0);
    bar();
    // ---- phase 1: B of tile t is dead -> stage tile t+2's B half 0
    if (t + 2 < NT) { stageB(t + 2, 0); stageB(t + 2, 64); }
    APHASE(1);
    bar();
    // ---- phase 2: stage tile t+2's B half 1
    if (t + 2 < NT) { stageB(t + 2, 128); stageB(t + 2, 192); }
    APHASE(2);
    bar();
    // ---- phase 3: A units 0,128 of tile t dead after quadrants 0-1 -> stage
    if (t + 2 < NT) { stageA(t + 2, 0); stageA(t + 2, 128); }
    APHASE(3);
    // ---- tile boundary: counted wait (tile t+1 staged; t+2's 6 stay in flight)
    if (t + 2 < NT)      { asm volatile("s_waitcnt vmcnt(6)" ::: "memory"); }
    else if (t + 1 < NT) { asm volatile("s_waitcnt vmcnt(0)" ::: "memory"); }
    bar();
#undef APHASE
  }

  float dtv = dtp[0];
  float omd = 1.0f - dtv;
#pragma unroll
  for (int mi = 0; mi < 8; ++mi) {
#pragma unroll
    for (int r4 = 0; r4 < 4; ++r4) {
      int row = tm * 256 + wr * 128 + mi * 16 + g * 4 + r4;
      float rs = rowscale[row];
      const float* xr = x + (size_t)row * N4096;
      float* orow = out + (size_t)row * N4096;
#pragma unroll
      for (int ni = 0; ni < 4; ++ni) {
        int col = tn * 256 + wc * 64 + ni * 16 + rr;
        orow[col] = xr[col] * omd + rs * acc[mi][ni][r4];
      }
    }
  }
}

extern "C" void kernel_launch(void* const* d_in, const int* in_sizes, int n_in,
                              void* d_out, int out_size, void* d_ws, size_t ws_size,
                              hipStream_t stream) {
  const float* x      = (const float*)d_in[0];
  const float* proj_w = (const float*)d_in[1];
  const float* proj_b = (const float*)d_in[2];
  const float* pi_w1  = (const float*)d_in[3];
  const float* pi_b1  = (const float*)d_in[4];
  const float* pi_w2  = (const float*)d_in[5];
  const float* pi_b2  = (const float*)d_in[6];
  const float* dt     = (const float*)d_in[7];
  float* out = (float*)d_out;

  char* ws = (char*)d_ws;
  const size_t MB = 1024 * 1024;
  __hip_bfloat16* W   = (__hip_bfloat16*)(ws);               // 32 MB
  __hip_bfloat16* XFT = (__hip_bfloat16*)(ws + 32 * MB);     // 32 MB
  float* z        = (float*)(ws + 64 * MB);                  // 256 KB
  float* sq       = (float*)(ws + 64 * MB + 256 * 1024);     // 16 KB
  float* dvec     = (float*)(ws + 64 * MB + 272 * 1024);     // 16 KB
  float* rowscale = (float*)(ws + 64 * MB + 288 * 1024);     // 16 KB

  (void)hipFuncSetAttribute((const void*)gemm8_kernel,
                            hipFuncAttributeMaxDynamicSharedMemorySize, 131072);

  zproj_kernel<<<256, 256, 0, stream>>>(x, proj_w, proj_b, z, sq);
  piq_kernel<<<512, 256, 0, stream>>>(z, sq, pi_w1, pi_b1, pi_w2, pi_b2, dvec);
  transpose_kernel<<<4096, 256, 0, stream>>>(x, XFT);
  wmat_kernel<<<512, 256, 0, stream>>>(z, sq, dvec, dt, W, rowscale);
  gemm8_kernel<<<256, 512, 131072, stream>>>(W, XFT, x, rowscale, dt, out);
}